// Round 6
// baseline (230.201 us; speedup 1.0000x reference)
//
#include <hip/hip_runtime.h>

// CRF NLL: B=1024, S=512, T=48.
// MFMA-batched forward algorithm: 16 batches per block, state Q = P^T
// (48 states x 16 batches). Step: C[j][b] = sum_k E'[k][j] * Q[k][b] via
// v_mfma_f32_16x16x16_bf16 (A = fixed E'^T, 3x3 tiles), then C *= w_s
// elementwise. KEY: 16x16x16 C/D layout (row=4q+r, col=lane&15) == B-operand
// layout (k=4q+i, n=lane&15) -> the state feeds the next step's B operand in
// registers. No LDS/readlane broadcast on the serial chain (R2-R5 bottleneck).
// 64 blocks x 3 waves: w0=forward half, w1=backward half, w2=gold score.
// Variable lengths via per-column freeze blend; 2^-6 folded into E';
// exact pow2 rescale (ds_bpermute column max) every 8 steps; bf16 state
// (f32 exponent range) with round-to-nearest pack.

#define T 48
#define SLEN 512
#define BATCH 1024
#define STT (SLEN * T)
#define NB 16
#define LOG2E 1.4426950408889634f
#define LN2   0.6931471805599453f
#define ESC   6.0f   // E' = exp(trans) * 2^-ESC; undone at finalize

typedef float f4 __attribute__((ext_vector_type(4)));
typedef short s4 __attribute__((ext_vector_type(4)));

#if __has_builtin(__builtin_amdgcn_mfma_f32_16x16x16bf16_1k)
#define MFMA(a, b, c) __builtin_amdgcn_mfma_f32_16x16x16bf16_1k((a), (b), (c), 0, 0, 0)
#else
static __device__ __forceinline__ f4 MFMA(s4 a, s4 b, f4 c) {
    f4 d;
    asm volatile("v_mfma_f32_16x16x16_bf16 %0, %1, %2, %3"
                 : "=v"(d) : "v"(a), "v"(b), "v"(c));
    return d;
}
#endif

__device__ __forceinline__ float bpermf(int addr, float v) {
    return __int_as_float(__builtin_amdgcn_ds_bpermute(addr, __float_as_int(v)));
}
__device__ __forceinline__ unsigned bfpk(float x, float y) {
    return ((__float_as_uint(x) + 0x8000u) >> 16) |
           ((__float_as_uint(y) + 0x8000u) & 0xffff0000u);
}
__device__ __forceinline__ s4 pk4(f4 v) {
    union { unsigned u[2]; s4 s; } c;
    c.u[0] = bfpk(v.x, v.y); c.u[1] = bfpk(v.z, v.w);
    return c.s;
}
__device__ __forceinline__ f4 e4(f4 v) {
    f4 r;
    r.x = exp2f(v.x * LOG2E); r.y = exp2f(v.y * LOG2E);
    r.z = exp2f(v.z * LOG2E); r.w = exp2f(v.w * LOG2E);
    return r;
}
__device__ __forceinline__ s4 mkfrag(const float* tr, int base, int step) {
    f4 e;
    e.x = exp2f(tr[base] * LOG2E - ESC);
    e.y = exp2f(tr[base + step] * LOG2E - ESC);
    e.z = exp2f(tr[base + 2 * step] * LOG2E - ESC);
    e.w = exp2f(tr[base + 3 * step] * LOG2E - ESC);
    return pk4(e);
}

#define BL(K, lv, V) { K.x = lv ? V.x : K.x; K.y = lv ? V.y : K.y; \
                       K.z = lv ? V.z : K.z; K.w = lv ? V.w : K.w; }

#define RESC { \
    float mv = fmaxf(fmaxf(fmaxf(K0.x, K0.y), fmaxf(K0.z, K0.w)), \
                     fmaxf(fmaxf(K1.x, K1.y), fmaxf(K1.z, K1.w))); \
    mv = fmaxf(mv, fmaxf(fmaxf(K2.x, K2.y), fmaxf(K2.z, K2.w))); \
    mv = fmaxf(mv, bpermf(a16, mv)); mv = fmaxf(mv, bpermf(a32, mv)); \
    int e_ = ((__float_as_int(mv) >> 23) & 255) - 127; \
    e_ = e_ < -120 ? -120 : (e_ > 120 ? 120 : e_); \
    float sc_ = __int_as_float((127 - e_) << 23); \
    K0 *= sc_; K1 *= sc_; K2 *= sc_; L += (float)e_; }

#define MFMA9 \
    f4 c0 = {0.f, 0.f, 0.f, 0.f}, c1 = {0.f, 0.f, 0.f, 0.f}, c2 = {0.f, 0.f, 0.f, 0.f}; \
    c0 = MFMA(A00, B0, c0); c1 = MFMA(A10, B0, c1); c2 = MFMA(A20, B0, c2); \
    c0 = MFMA(A01, B1, c0); c1 = MFMA(A11, B1, c1); c2 = MFMA(A21, B1, c2); \
    c0 = MFMA(A02, B2, c0); c1 = MFMA(A12, B2, c1); c2 = MFMA(A22, B2, c2);

__global__ __launch_bounds__(192, 1) void crf_kernel(
    const float* __restrict__ em,      // (B,S,T)
    const int*   __restrict__ tags,    // (B,S)
    const float* __restrict__ mask,    // (B,S)
    const float* __restrict__ tr,      // (T,T)
    const float* __restrict__ start_t, // (T,)
    const float* __restrict__ end_t,   // (T,)
    float*       __restrict__ out)     // scalar
{
    const int tid  = threadIdx.x;
    const int wv   = tid >> 6;
    const int lane = tid & 63;
    const int l15  = lane & 15;
    const int q    = lane >> 4;
    const int bg   = blockIdx.x * NB;

    __shared__ float sP[NB * T];
    __shared__ float sLf[NB];
    __shared__ float sGold[NB];

    // ---- lengths: 4 lanes per batch, then bpermute-redistribute ----
    const int bb = lane >> 2, q3 = lane & 3;
    {
        // computed by every wave independently (no barrier needed)
    }
    const f4* m4 = (const f4*)(mask + (size_t)(bg + bb) * SLEN + q3 * 128);
    float ms = 0.f;
    #pragma unroll 8
    for (int i = 0; i < 32; ++i) { f4 v = m4[i]; ms += (v.x + v.y) + (v.z + v.w); }
    ms += __shfl_xor(ms, 1); ms += __shfl_xor(ms, 2);
    const int len_team = (int)(ms + 0.5f);
    const int a16 = (lane ^ 16) << 2, a32 = (lane ^ 32) << 2;
    const int lenc = __builtin_amdgcn_ds_bpermute(l15 << 4, len_team); // from lane l15*4
    const int nf_c = (lenc - 1) >> 1;
    const int nb_c = (lenc - 1) - nf_c;

    if (wv == 2) {
        // ================= GOLD wave =================
        const int bi = bg + bb;
        const int*   tg = tags + (size_t)bi * SLEN;
        const float* eb = em + (size_t)bi * STT;
        float g0 = 0.f, g1 = 0.f;
        int i = 1 + q3;
        for (; i + 12 < len_team; i += 16) {
            int c0 = tg[i],      p0 = tg[i - 1];
            int c1 = tg[i + 4],  p1 = tg[i + 3];
            int c2 = tg[i + 8],  p2 = tg[i + 7];
            int c3 = tg[i + 12], p3 = tg[i + 11];
            g0 += tr[c0 * T + p0] + eb[i * T + c0];
            g1 += tr[c1 * T + p1] + eb[(i + 4) * T + c1];
            g0 += tr[c2 * T + p2] + eb[(i + 8) * T + c2];
            g1 += tr[c3 * T + p3] + eb[(i + 12) * T + c3];
        }
        for (; i < len_team; i += 4) {
            int c = tg[i], p = tg[i - 1];
            g0 += tr[c * T + p] + eb[i * T + c];
        }
        float g = g0 + g1;
        g += __shfl_xor(g, 1); g += __shfl_xor(g, 2);
        if (q3 == 0) {
            int t0 = tg[0], tl = tg[len_team - 1];
            sGold[bb] = g + start_t[t0] + eb[t0] + end_t[tl];
        }
    } else if (wv == 0) {
        // ================= FORWARD wave =================
        // A[m=j][k] = E'[k][j] = exp(tr[k*T + j]) * 2^-ESC
        s4 A00 = mkfrag(tr, (0  + 4*q) * T + 0  + l15, T);
        s4 A10 = mkfrag(tr, (0  + 4*q) * T + 16 + l15, T);
        s4 A20 = mkfrag(tr, (0  + 4*q) * T + 32 + l15, T);
        s4 A01 = mkfrag(tr, (16 + 4*q) * T + 0  + l15, T);
        s4 A11 = mkfrag(tr, (16 + 4*q) * T + 16 + l15, T);
        s4 A21 = mkfrag(tr, (16 + 4*q) * T + 32 + l15, T);
        s4 A02 = mkfrag(tr, (32 + 4*q) * T + 0  + l15, T);
        s4 A12 = mkfrag(tr, (32 + 4*q) * T + 16 + l15, T);
        s4 A22 = mkfrag(tr, (32 + 4*q) * T + 32 + l15, T);

        int mx = nf_c;
        mx = max(mx, __shfl_xor(mx, 1)); mx = max(mx, __shfl_xor(mx, 2));
        mx = max(mx, __shfl_xor(mx, 4)); mx = max(mx, __shfl_xor(mx, 8));

        const f4* p4b = (const f4*)(em + (size_t)(bg + l15) * STT);
        const f4* st4 = (const f4*)start_t;
        f4 K0, K1, K2;
        {
            f4 e0 = p4b[q], e1 = p4b[4 + q], e2 = p4b[8 + q];
            K0 = e4(e0 + st4[q]); K1 = e4(e1 + st4[4 + q]); K2 = e4(e2 + st4[8 + q]);
        }
        float L = 0.f;
        s4 B0 = pk4(K0), B1 = pk4(K1), B2 = pk4(K2);

        f4 R00,R01,R02, R10,R11,R12, R20,R21,R22, R30,R31,R32, W0,W1,W2;
        #define LDF(Sa,Sb,Sc, sidx) { int o_ = (sidx)*12 + q; Sa = p4b[o_]; Sb = p4b[o_+4]; Sc = p4b[o_+8]; }
        LDF(R00,R01,R02, 1) LDF(R10,R11,R12, 2) LDF(R20,R21,R22, 3) LDF(R30,R31,R32, 4)
        W0 = e4(R00); W1 = e4(R01); W2 = e4(R02);
        LDF(R00,R01,R02, 5)

        #define FIT(dd, Sa,Sb,Sc, RS) { \
            MFMA9 \
            bool lv = (dd) <= nf_c; \
            c0 = c0 * W0; c1 = c1 * W1; c2 = c2 * W2; \
            BL(K0, lv, c0) BL(K1, lv, c1) BL(K2, lv, c2) \
            if ((RS) && (((dd) & 7) == 0)) RESC \
            B0 = pk4(K0); B1 = pk4(K1); B2 = pk4(K2); \
            W0 = e4(Sa); W1 = e4(Sb); W2 = e4(Sc); \
            LDF(Sa,Sb,Sc, (dd) + 5) }

        int d = 1;
        for (; d + 3 <= mx; d += 4) {
            FIT(d,     R10,R11,R12, 0)
            FIT(d + 1, R20,R21,R22, 0)
            FIT(d + 2, R30,R31,R32, 0)
            FIT(d + 3, R00,R01,R02, 1)
        }
        if (d <= mx) { FIT(d, R10,R11,R12, 0)
            if (d + 1 <= mx) { FIT(d + 1, R20,R21,R22, 0)
                if (d + 2 <= mx) FIT(d + 2, R30,R31,R32, 0) } }
        #undef FIT
        #undef LDF

        f4* sp4 = (f4*)sP;
        int ob = l15 * 12 + q;
        sp4[ob] = K0; sp4[ob + 4] = K1; sp4[ob + 8] = K2;
        if (lane < 16) sLf[lane] = L + ESC * (float)nf_c;
    }

    float uK0x=0.f; // placeholder to keep structure simple
    if (wv == 1) {
        // ================= BACKWARD wave =================
        // A[m=k][kk=j] = E'[m][kk] = exp(tr[m*T + kk]) * 2^-ESC
        s4 A00 = mkfrag(tr, (0  + l15) * T + 0  + 4*q, 1);
        s4 A10 = mkfrag(tr, (16 + l15) * T + 0  + 4*q, 1);
        s4 A20 = mkfrag(tr, (32 + l15) * T + 0  + 4*q, 1);
        s4 A01 = mkfrag(tr, (0  + l15) * T + 16 + 4*q, 1);
        s4 A11 = mkfrag(tr, (16 + l15) * T + 16 + 4*q, 1);
        s4 A21 = mkfrag(tr, (32 + l15) * T + 16 + 4*q, 1);
        s4 A02 = mkfrag(tr, (0  + l15) * T + 32 + 4*q, 1);
        s4 A12 = mkfrag(tr, (16 + l15) * T + 32 + 4*q, 1);
        s4 A22 = mkfrag(tr, (32 + l15) * T + 32 + 4*q, 1);

        int mx = nb_c;
        mx = max(mx, __shfl_xor(mx, 1)); mx = max(mx, __shfl_xor(mx, 2));
        mx = max(mx, __shfl_xor(mx, 4)); mx = max(mx, __shfl_xor(mx, 8));

        const f4* p4b = (const f4*)(em + (size_t)(bg + l15) * STT);
        const f4* en4 = (const f4*)end_t;
        f4 K0 = e4(en4[q]), K1 = e4(en4[4 + q]), K2 = e4(en4[8 + q]);
        float L = 0.f;
        s4 B0, B1, B2;

        f4 R00,R01,R02, R10,R11,R12, R20,R21,R22, R30,R31,R32, W0,W1,W2;
        #define LDB(Sa,Sb,Sc, dd) { int sb_ = lenc - 1 - (dd); sb_ = sb_ < 0 ? 0 : sb_; \
            int o_ = sb_ * 12 + q; Sa = p4b[o_]; Sb = p4b[o_+4]; Sc = p4b[o_+8]; }
        LDB(R00,R01,R02, 0) LDB(R10,R11,R12, 1) LDB(R20,R21,R22, 2) LDB(R30,R31,R32, 3)
        W0 = e4(R00); W1 = e4(R01); W2 = e4(R02);
        LDB(R00,R01,R02, 4)

        #define BIT(dd, Sa,Sb,Sc, RS) { \
            f4 t0 = K0 * W0, t1 = K1 * W1, t2 = K2 * W2; \
            B0 = pk4(t0); B1 = pk4(t1); B2 = pk4(t2); \
            MFMA9 \
            bool lv = (dd) < nb_c; \
            BL(K0, lv, c0) BL(K1, lv, c1) BL(K2, lv, c2) \
            if ((RS) && (((dd) & 7) == 7)) RESC \
            W0 = e4(Sa); W1 = e4(Sb); W2 = e4(Sc); \
            LDB(Sa,Sb,Sc, (dd) + 5) }

        int d = 0;
        for (; d + 4 <= mx; d += 4) {
            BIT(d,     R10,R11,R12, 0)
            BIT(d + 1, R20,R21,R22, 0)
            BIT(d + 2, R30,R31,R32, 0)
            BIT(d + 3, R00,R01,R02, 1)
        }
        if (d < mx) { BIT(d, R10,R11,R12, 0)
            if (d + 1 < mx) { BIT(d + 1, R20,R21,R22, 0)
                if (d + 2 < mx) BIT(d + 2, R30,R31,R32, 0) } }
        #undef BIT
        #undef LDB

        __syncthreads();

        // ---- combine: Z[b] = sum_j P[j][b] * U[j][b] ----
        const f4* sp4 = (const f4*)sP;
        int ob = l15 * 12 + q;
        f4 p0 = sp4[ob], p1 = sp4[ob + 4], p2 = sp4[ob + 8];
        float part = p0.x * K0.x;
        part = fmaf(p0.y, K0.y, part); part = fmaf(p0.z, K0.z, part); part = fmaf(p0.w, K0.w, part);
        part = fmaf(p1.x, K1.x, part); part = fmaf(p1.y, K1.y, part);
        part = fmaf(p1.z, K1.z, part); part = fmaf(p1.w, K1.w, part);
        part = fmaf(p2.x, K2.x, part); part = fmaf(p2.y, K2.y, part);
        part = fmaf(p2.z, K2.z, part); part = fmaf(p2.w, K2.w, part);
        part += bpermf(a16, part); part += bpermf(a32, part);

        float res = 0.f;
        if (lane < 16) {
            float lz = (sLf[lane] + (L + ESC * (float)nb_c) + log2f(part)) * LN2;
            res = lz - sGold[lane];
        }
        #pragma unroll
        for (int m = 32; m >= 1; m >>= 1) res += __shfl_xor(res, m);
        if (lane == 0) atomicAdd(out, res * (1.0f / (float)BATCH));
    } else {
        __syncthreads();  // waves 0 and 2 meet wave 1's barrier
    }
    (void)uK0x;
}

extern "C" void kernel_launch(void* const* d_in, const int* in_sizes, int n_in,
                              void* d_out, int out_size, void* d_ws, size_t ws_size,
                              hipStream_t stream) {
    const float* em      = (const float*)d_in[0];
    const int*   tags    = (const int*)  d_in[1];
    const float* mask    = (const float*)d_in[2];
    const float* trans   = (const float*)d_in[3];
    const float* start_t = (const float*)d_in[4];
    const float* end_t   = (const float*)d_in[5];
    float* out = (float*)d_out;

    hipMemsetAsync(out, 0, sizeof(float), stream);
    crf_kernel<<<BATCH / NB, 192, 0, stream>>>(em, tags, mask, trans, start_t, end_t, out);
}

// Round 7
// 216.683 us; speedup vs baseline: 1.0624x; 1.0624x over previous
//
#include <hip/hip_runtime.h>

// CRF NLL: B=1024, S=512, T=48.
// Grid = 128 blocks x 256 thr:
//   blocks 0..63  : chain blocks, 16 batches each, 4 waves:
//     w0 = fwd MFMA consumer, w1 = bwd MFMA consumer,
//     w2 = fwd emission producer, w3 = bwd emission producer.
//     Producers load em chunks (8 steps x 16 batches), compute w=exp(em),
//     store f16 into double-buffered padded LDS. Consumers' K-loop has ZERO
//     VMEM -> the compiler's vmcnt(0)-drain (the R2-R6 per-step ~500-700cyc
//     memory-latency tax) moves into producer waves, overlapped.
//   blocks 64..127: gold-score blocks (16 batches, 16 lanes each).
// Recursion (validated R6): state Q=P^T in MFMA C-layout; step = 3x3 tile
// mfma_f32_16x16x16_bf16 with fixed A=E'; C/D layout == B layout so state
// feeds next step's B in registers. E' = exp(trans)*2^-6; exact pow2
// rescale every 8 steps; per-column freeze blend for variable lengths.

#define T 48
#define SLEN 512
#define BATCH 1024
#define STT (SLEN * T)
#define NB 16
#define NBLK 64
#define CH 8
#define PADH 52   // halfs per (s,b) row in staged LDS (conflict-free, b64-aligned)
#define LOG2E 1.4426950408889634f
#define LN2   0.6931471805599453f
#define ESC   6.0f

typedef float f4 __attribute__((ext_vector_type(4)));
typedef short s4 __attribute__((ext_vector_type(4)));
typedef _Float16 h4v __attribute__((ext_vector_type(4)));
typedef h4v h4 __attribute__((may_alias));

#if __has_builtin(__builtin_amdgcn_mfma_f32_16x16x16bf16_1k)
#define MFMA(a, b, c) __builtin_amdgcn_mfma_f32_16x16x16bf16_1k((a), (b), (c), 0, 0, 0)
#else
static __device__ __forceinline__ f4 MFMA(s4 a, s4 b, f4 c) {
    f4 d;
    asm volatile("v_mfma_f32_16x16x16_bf16 %0, %1, %2, %3"
                 : "=v"(d) : "v"(a), "v"(b), "v"(c));
    return d;
}
#endif

__device__ __forceinline__ float bpermf(int addr, float v) {
    return __int_as_float(__builtin_amdgcn_ds_bpermute(addr, __float_as_int(v)));
}
__device__ __forceinline__ unsigned bfpk(float x, float y) {
    return ((__float_as_uint(x) + 0x8000u) >> 16) |
           ((__float_as_uint(y) + 0x8000u) & 0xffff0000u);
}
__device__ __forceinline__ s4 pk4(f4 v) {
    union { unsigned u[2]; s4 s; } c;
    c.u[0] = bfpk(v.x, v.y); c.u[1] = bfpk(v.z, v.w);
    return c.s;
}
__device__ __forceinline__ f4 e4(f4 v) {
    f4 r;
    r.x = exp2f(v.x * LOG2E); r.y = exp2f(v.y * LOG2E);
    r.z = exp2f(v.z * LOG2E); r.w = exp2f(v.w * LOG2E);
    return r;
}
__device__ __forceinline__ h4 toh4(f4 v) { return __builtin_convertvector(v, h4v); }
__device__ __forceinline__ f4 tof4(h4 h) { return __builtin_convertvector(h, f4); }
__device__ __forceinline__ s4 mkfrag(const float* tr, int base, int step) {
    f4 e;
    e.x = exp2f(tr[base] * LOG2E - ESC);
    e.y = exp2f(tr[base + step] * LOG2E - ESC);
    e.z = exp2f(tr[base + 2 * step] * LOG2E - ESC);
    e.w = exp2f(tr[base + 3 * step] * LOG2E - ESC);
    return pk4(e);
}

#define BL(K, lv, V) { K.x = lv ? V.x : K.x; K.y = lv ? V.y : K.y; \
                       K.z = lv ? V.z : K.z; K.w = lv ? V.w : K.w; }

#define RESC { \
    float mv = fmaxf(fmaxf(fmaxf(K0.x, K0.y), fmaxf(K0.z, K0.w)), \
                     fmaxf(fmaxf(K1.x, K1.y), fmaxf(K1.z, K1.w))); \
    mv = fmaxf(mv, fmaxf(fmaxf(K2.x, K2.y), fmaxf(K2.z, K2.w))); \
    mv = fmaxf(mv, bpermf(a16, mv)); mv = fmaxf(mv, bpermf(a32, mv)); \
    int e_ = ((__float_as_int(mv) >> 23) & 255) - 127; \
    e_ = e_ < -120 ? -120 : (e_ > 120 ? 120 : e_); \
    float sc_ = __int_as_float((127 - e_) << 23); \
    K0 *= sc_; K1 *= sc_; K2 *= sc_; L += (float)e_; }

#define MFMA9 \
    f4 c0 = {0.f,0.f,0.f,0.f}, c1 = {0.f,0.f,0.f,0.f}, c2 = {0.f,0.f,0.f,0.f}; \
    c0 = MFMA(A00, B0, c0); c1 = MFMA(A10, B0, c1); c2 = MFMA(A20, B0, c2); \
    c0 = MFMA(A01, B1, c0); c1 = MFMA(A11, B1, c1); c2 = MFMA(A21, B1, c2); \
    c0 = MFMA(A02, B2, c0); c1 = MFMA(A12, B2, c1); c2 = MFMA(A22, B2, c2);

// producer: load 8 steps x (3 f4 per batch-lane-group), exp, store f16 padded
#define STAGE(c_, DIRIDX, SGEXPR) { \
    f4 r_[24]; \
    _Pragma("unroll") \
    for (int s_ = 0; s_ < CH; ++s_) { \
        int sg_ = (SGEXPR); \
        sg_ = sg_ < 0 ? 0 : (sg_ > SLEN - 1 ? SLEN - 1 : sg_); \
        const f4* src_ = (const f4*)(eb + (size_t)sg_ * T); \
        r_[s_*3+0] = src_[p3*3+0]; r_[s_*3+1] = src_[p3*3+1]; r_[s_*3+2] = src_[p3*3+2]; \
    } \
    h4* dst_ = (h4*)sEm[DIRIDX][(c_) & 1]; \
    _Pragma("unroll") \
    for (int s_ = 0; s_ < CH; ++s_) { \
        int o_ = (s_ * 16 + bat) * 13 + p3 * 3; \
        dst_[o_+0] = toh4(e4(r_[s_*3+0])); \
        dst_[o_+1] = toh4(e4(r_[s_*3+1])); \
        dst_[o_+2] = toh4(e4(r_[s_*3+2])); \
    } }

__global__ __launch_bounds__(256, 1) void crf_kernel(
    const float* __restrict__ em,      // (B,S,T)
    const int*   __restrict__ tags,    // (B,S)
    const float* __restrict__ mask,    // (B,S)
    const float* __restrict__ tr,      // (T,T)
    const float* __restrict__ start_t, // (T,)
    const float* __restrict__ end_t,   // (T,)
    float*       __restrict__ out)     // scalar
{
    const int tid = threadIdx.x;

    if (blockIdx.x >= NBLK) {
        // ================= GOLD blocks =================
        const int gb  = blockIdx.x - NBLK;
        const int bat = tid >> 4, lq = tid & 15;
        const int bi  = gb * NB + bat;
        const float* mb = mask + (size_t)bi * SLEN;
        const f4* m4 = (const f4*)mb;
        float ms = 0.f;
        #pragma unroll
        for (int i = 0; i < 8; ++i) { f4 v = m4[lq * 8 + i]; ms += (v.x + v.y) + (v.z + v.w); }
        ms += __shfl_xor(ms, 1); ms += __shfl_xor(ms, 2);
        ms += __shfl_xor(ms, 4); ms += __shfl_xor(ms, 8);
        const int len = (int)(ms + 0.5f);
        const int*   tg = tags + (size_t)bi * SLEN;
        const float* eb = em + (size_t)bi * STT;
        float g = 0.f;
        for (int i = 1 + lq; i < len; i += 16) {
            int cc = tg[i], pp = tg[i - 1];
            g += tr[cc * T + pp] + eb[(size_t)i * T + cc];
        }
        g += __shfl_xor(g, 1); g += __shfl_xor(g, 2);
        g += __shfl_xor(g, 4); g += __shfl_xor(g, 8);
        if (lq == 0) {
            int t0 = tg[0], tl = tg[len - 1];
            float gold = g + start_t[t0] + eb[t0] + end_t[tl];
            atomicAdd(out, -gold * (1.0f / (float)BATCH));
        }
        return;
    }

    // ================= CHAIN blocks =================
    const int wv   = tid >> 6;
    const int lane = tid & 63;
    const int l15  = lane & 15;
    const int q    = lane >> 4;
    const int bg   = blockIdx.x * NB;

    __shared__ __align__(16) _Float16 sEm[2][2][CH * 16 * PADH]; // 53 KB
    __shared__ float sP[NB * T];
    __shared__ float sLf[NB];

    // ---- lengths (all waves identically) ----
    const int bb = lane >> 2, p3 = lane & 3;
    const f4* m4 = (const f4*)(mask + (size_t)(bg + bb) * SLEN + p3 * 128);
    float ms = 0.f;
    #pragma unroll 8
    for (int i = 0; i < 32; ++i) { f4 v = m4[i]; ms += (v.x + v.y) + (v.z + v.w); }
    ms += __shfl_xor(ms, 1); ms += __shfl_xor(ms, 2);
    const int len_team = (int)(ms + 0.5f);           // length of batch (lane>>2)
    const int lenc = __builtin_amdgcn_ds_bpermute(l15 << 4, len_team); // col l15's len
    const int nf_c = (lenc - 1) - ((lenc - 1) >> 1);
    const int nb_c = (lenc - 1) >> 1;
    const int a16 = (lane ^ 16) << 2, a32 = (lane ^ 32) << 2;

    int mxf = nf_c;
    mxf = max(mxf, __shfl_xor(mxf, 1)); mxf = max(mxf, __shfl_xor(mxf, 2));
    mxf = max(mxf, __shfl_xor(mxf, 4)); mxf = max(mxf, __shfl_xor(mxf, 8));
    const int NCH = (mxf + 7) >> 3;                  // nf >= nb -> covers both dirs

    s4 A00{}, A10{}, A20{}, A01{}, A11{}, A21{}, A02{}, A12{}, A22{};
    f4 K0{}, K1{}, K2{};
    s4 B0{}, B1{}, B2{};
    float L = 0.f;
    const int bat = bb;
    const float* eb = em + (size_t)(bg + bat) * STT; // producers' batch base
    const int lb = len_team;

    if (wv == 0) {
        // fwd: A[m=j][k] = E'[k][j]
        A00 = mkfrag(tr, (0  + 4*q) * T + 0  + l15, T);
        A10 = mkfrag(tr, (0  + 4*q) * T + 16 + l15, T);
        A20 = mkfrag(tr, (0  + 4*q) * T + 32 + l15, T);
        A01 = mkfrag(tr, (16 + 4*q) * T + 0  + l15, T);
        A11 = mkfrag(tr, (16 + 4*q) * T + 16 + l15, T);
        A21 = mkfrag(tr, (16 + 4*q) * T + 32 + l15, T);
        A02 = mkfrag(tr, (32 + 4*q) * T + 0  + l15, T);
        A12 = mkfrag(tr, (32 + 4*q) * T + 16 + l15, T);
        A22 = mkfrag(tr, (32 + 4*q) * T + 32 + l15, T);
        const f4* p4b = (const f4*)(em + (size_t)(bg + l15) * STT);
        const f4* st4 = (const f4*)start_t;
        K0 = e4(p4b[q] + st4[q]);
        K1 = e4(p4b[4 + q] + st4[4 + q]);
        K2 = e4(p4b[8 + q] + st4[8 + q]);
        B0 = pk4(K0); B1 = pk4(K1); B2 = pk4(K2);
    } else if (wv == 1) {
        // bwd: A[m=k][j]
        A00 = mkfrag(tr, (0  + l15) * T + 0  + 4*q, 1);
        A10 = mkfrag(tr, (16 + l15) * T + 0  + 4*q, 1);
        A20 = mkfrag(tr, (32 + l15) * T + 0  + 4*q, 1);
        A01 = mkfrag(tr, (0  + l15) * T + 16 + 4*q, 1);
        A11 = mkfrag(tr, (16 + l15) * T + 16 + 4*q, 1);
        A21 = mkfrag(tr, (32 + l15) * T + 16 + 4*q, 1);
        A02 = mkfrag(tr, (0  + l15) * T + 32 + 4*q, 1);
        A12 = mkfrag(tr, (16 + l15) * T + 32 + 4*q, 1);
        A22 = mkfrag(tr, (32 + l15) * T + 32 + 4*q, 1);
        const f4* en4 = (const f4*)end_t;
        K0 = e4(en4[q]); K1 = e4(en4[4 + q]); K2 = e4(en4[8 + q]);
    } else if (wv == 2) {
        STAGE(0, 0, 0 * CH + 1 + s_)
    } else {
        STAGE(0, 1, lb - 1 - (0 * CH + s_))
    }

    __syncthreads();   // buf0 ready

    for (int c = 0; c < NCH; ++c) {
        if (wv == 0) {
            const h4* wb = ((const h4*)sEm[0][c & 1]) + l15 * 13 + q;
            #pragma unroll
            for (int s = 0; s < CH; ++s) {
                f4 W0 = tof4(wb[s * 208 + 0]);
                f4 W1 = tof4(wb[s * 208 + 4]);
                f4 W2 = tof4(wb[s * 208 + 8]);
                const int d = c * CH + 1 + s;
                MFMA9
                bool lv = d <= nf_c;
                c0 = c0 * W0; c1 = c1 * W1; c2 = c2 * W2;
                BL(K0, lv, c0) BL(K1, lv, c1) BL(K2, lv, c2)
                if (s == CH - 1) RESC
                B0 = pk4(K0); B1 = pk4(K1); B2 = pk4(K2);
            }
        } else if (wv == 1) {
            const h4* wb = ((const h4*)sEm[1][c & 1]) + l15 * 13 + q;
            #pragma unroll
            for (int s = 0; s < CH; ++s) {
                f4 W0 = tof4(wb[s * 208 + 0]);
                f4 W1 = tof4(wb[s * 208 + 4]);
                f4 W2 = tof4(wb[s * 208 + 8]);
                f4 t0 = K0 * W0, t1 = K1 * W1, t2 = K2 * W2;
                B0 = pk4(t0); B1 = pk4(t1); B2 = pk4(t2);
                const int dd = c * CH + s;
                MFMA9
                bool lv = dd < nb_c;
                BL(K0, lv, c0) BL(K1, lv, c1) BL(K2, lv, c2)
                if (s == CH - 1) RESC
            }
        } else if (wv == 2) {
            if (c + 1 < NCH) STAGE(c + 1, 0, (c + 1) * CH + 1 + s_)
        } else {
            if (c + 1 < NCH) STAGE(c + 1, 1, lb - 1 - ((c + 1) * CH + s_))
        }
        __syncthreads();
    }

    if (wv == 0) {
        f4* sp4 = (f4*)sP;
        int ob = l15 * 12 + q;
        sp4[ob] = K0; sp4[ob + 4] = K1; sp4[ob + 8] = K2;
        if (lane < 16) sLf[lane] = L + ESC * (float)nf_c;
    }
    __syncthreads();

    if (wv == 1) {
        const f4* sp4 = (const f4*)sP;
        int ob = l15 * 12 + q;
        f4 p0 = sp4[ob], p1 = sp4[ob + 4], p2 = sp4[ob + 8];
        float part = p0.x * K0.x;
        part = fmaf(p0.y, K0.y, part); part = fmaf(p0.z, K0.z, part); part = fmaf(p0.w, K0.w, part);
        part = fmaf(p1.x, K1.x, part); part = fmaf(p1.y, K1.y, part);
        part = fmaf(p1.z, K1.z, part); part = fmaf(p1.w, K1.w, part);
        part = fmaf(p2.x, K2.x, part); part = fmaf(p2.y, K2.y, part);
        part = fmaf(p2.z, K2.z, part); part = fmaf(p2.w, K2.w, part);
        part += bpermf(a16, part); part += bpermf(a32, part);

        float res = 0.f;
        if (lane < 16) {
            float lz = (sLf[lane] + (L + ESC * (float)nb_c) + log2f(part)) * LN2;
            res = lz;
        }
        #pragma unroll
        for (int m = 32; m >= 1; m >>= 1) res += __shfl_xor(res, m);
        if (lane == 0) atomicAdd(out, res * (1.0f / (float)BATCH));
    }
}

extern "C" void kernel_launch(void* const* d_in, const int* in_sizes, int n_in,
                              void* d_out, int out_size, void* d_ws, size_t ws_size,
                              hipStream_t stream) {
    const float* em      = (const float*)d_in[0];
    const int*   tags    = (const int*)  d_in[1];
    const float* mask    = (const float*)d_in[2];
    const float* trans   = (const float*)d_in[3];
    const float* start_t = (const float*)d_in[4];
    const float* end_t   = (const float*)d_in[5];
    float* out = (float*)d_out;

    hipMemsetAsync(out, 0, sizeof(float), stream);
    crf_kernel<<<NBLK + BATCH / NB, 256, 0, stream>>>(em, tags, mask, trans, start_t, end_t, out);
}